// Round 13
// baseline (223.589 us; speedup 1.0000x reference)
//
#include <hip/hip_runtime.h>
#include <stdint.h>

#define SEQ   2048
#define DMODEL 2048
#define NQH   32
#define NKVH  8
#define HDIM  64
#define QN    (NQH*HDIM)    // 2048
#define KVNN  (NKVH*HDIM)   // 512

typedef __bf16 bf16x8 __attribute__((ext_vector_type(8)));
typedef float  f32x4  __attribute__((ext_vector_type(4)));
typedef unsigned short u16;

// f32 -> bf16 RNE via native cast: compiler emits the hardware cvt.
__device__ __forceinline__ u16 f2bf(float f) {
  __bf16 h = (__bf16)f;
  return __builtin_bit_cast(u16, h);
}
__device__ __forceinline__ float bf2f(u16 b) {
  return __builtin_bit_cast(float, (uint32_t)b << 16);
}
__device__ __forceinline__ float fexp2(float x) {
#if __has_builtin(__builtin_amdgcn_exp2f)
  return __builtin_amdgcn_exp2f(x);   // bare v_exp_f32
#else
  return __expf(0.69314718056f * x);  // hazard-safe fallback
#endif
}
__device__ __forceinline__ bool probe_is_f32(const uint32_t* p) {
  return (p[0] & 0xFFFFu) == 0u;   // cos[0]=1.0: f32->0x3F800000, bf16 pair->0x3F803F80
}

// global -> LDS direct DMA, 16B per lane, LDS dest = uniform base + lane*16
__device__ __forceinline__ void glds16(const u16* g, void* lds) {
  __builtin_amdgcn_global_load_lds(
      (const __attribute__((address_space(1))) uint32_t*)g,
      (__attribute__((address_space(3))) uint32_t*)lds, 16, 0, 0);
}
// Counted vmem waits (T4) + raw barrier.
__device__ __forceinline__ void wait_vm6() { asm volatile("s_waitcnt vmcnt(6)" ::: "memory"); }
__device__ __forceinline__ void wait_vm3() { asm volatile("s_waitcnt vmcnt(3)" ::: "memory"); }
__device__ __forceinline__ void wait_vm0() { asm volatile("s_waitcnt vmcnt(0)" ::: "memory"); }
__device__ __forceinline__ void raw_barrier() { __builtin_amdgcn_s_barrier(); }
__device__ __forceinline__ void mem_pin() { asm volatile("" ::: "memory"); }

// ---------------------------------------------------------------------------
// Fused input conversion: all 7 inputs -> bf16 copies in ws (8 elts/thread).
// ---------------------------------------------------------------------------
__global__ __launch_bounds__(256)
void conv_all(const void* __restrict__ X, const void* __restrict__ cosv,
              const void* __restrict__ sinv, const void* __restrict__ wq,
              const void* __restrict__ wk, const void* __restrict__ wv,
              const void* __restrict__ wo,
              u16* __restrict__ Xc, u16* __restrict__ cosc, u16* __restrict__ sinc,
              u16* __restrict__ wqc, u16* __restrict__ wkc, u16* __restrict__ wvc,
              u16* __restrict__ woc)
{
  const bool f32in = probe_is_f32((const uint32_t*)cosv);
  const long t = (long)blockIdx.x * 256 + threadIdx.x;
  const void* src; u16* dst; long off;
  if      (t < 524288L)  { src = X;    dst = Xc;   off = t; }
  else if (t < 1048576L) { src = wq;   dst = wqc;  off = t - 524288L; }
  else if (t < 1179648L) { src = wk;   dst = wkc;  off = t - 1048576L; }
  else if (t < 1310720L) { src = wv;   dst = wvc;  off = t - 1179648L; }
  else if (t < 1835008L) { src = wo;   dst = woc;  off = t - 1310720L; }
  else if (t < 1851392L) { src = cosv; dst = cosc; off = t - 1835008L; }
  else                   { src = sinv; dst = sinc; off = t - 1851392L; }
  if (f32in) {
    const float4* s = (const float4*)src;
    float4 a = s[2*off], b = s[2*off + 1];
    union { u16 h[8]; uint4 u; } o;
    o.h[0]=f2bf(a.x); o.h[1]=f2bf(a.y); o.h[2]=f2bf(a.z); o.h[3]=f2bf(a.w);
    o.h[4]=f2bf(b.x); o.h[5]=f2bf(b.y); o.h[6]=f2bf(b.z); o.h[7]=f2bf(b.w);
    *(uint4*)(dst + off*8) = o.u;
  } else {
    *(uint4*)(dst + off*8) = ((const uint4*)src)[off];
  }
}

// ---------------------------------------------------------------------------
// Merged QKV projection, 64m x 128n tiles, 4 waves/block, QUAD-buffered
// global_load_lds with counted vmcnt and ONE raw barrier per K-step:
// tile t+3 is staged into tile t-1's slot, and the top-of-iter barrier
// already proves all waves finished reading t-1 (during iter t-1) -> the
// old post-MFMA barrier is redundant at 4-buffer spacing.  Halves barrier
// count (round-12 lesson: 2-phase loop is sync-bound, not LDS/conflict-
// bound).  + T2 bank swizzle (conflicts=0, round-12) + fused RoPE-K /
// V-transpose epilogues.  Grid 24 x 32 = 768 blocks (3/CU, 48KB LDS).
// ---------------------------------------------------------------------------
__global__ __launch_bounds__(256, 4)
void gemm_qkv(const u16* __restrict__ A,
              const u16* __restrict__ wq, const u16* __restrict__ wk,
              const u16* __restrict__ wv,
              u16* __restrict__ Qb, u16* __restrict__ Kb, u16* __restrict__ Vtg,
              const u16* __restrict__ cosb, const u16* __restrict__ sinb)
{
  __shared__ __align__(16) u16 As[4][64][32];    // 16 KB
  __shared__ __align__(16) u16 Bs[4][128][32];   // 32 KB
  const int tid  = threadIdx.x;
  const int wave = tid >> 6;
  const int lane = tid & 63;
  const int quad = lane >> 4;
  const int l16  = lane & 15;
  const int m0 = blockIdx.y * 64;
  const int n0 = blockIdx.x * 128;
  const int wm = (wave & 1) * 32;
  const int wn = (wave >> 1) * 64;
  const int K = DMODEL;
  const int lr = lane >> 2;                      // 0..15 row within chunk
  const int lcs = (((lane & 3) ^ ((lr >> 1) & 3)) * 8);  // swizzled src col
  const int rc  = (quad ^ ((l16 >> 1) & 3)) * 8;         // swizzled read col

  const u16* Bb; int mode, nc0;      // 0=Q, 1=K(rope), 2=V(transpose)
  if (n0 < 2048)      { Bb = wq + (size_t)n0 * K;          mode = 0; nc0 = n0; }
  else if (n0 < 2560) { Bb = wk + (size_t)(n0 - 2048) * K; mode = 1; nc0 = n0 - 2048; }
  else                { Bb = wv + (size_t)(n0 - 2560) * K; mode = 2; nc0 = n0 - 2560; }

  f32x4 acc[2][4];
  #pragma unroll
  for (int i = 0; i < 2; i++)
    #pragma unroll
    for (int j = 0; j < 4; j++)
      acc[i][j] = (f32x4){0.f, 0.f, 0.f, 0.f};

  // wave w stages: A chunk w (rows 16w..16w+15), B chunks w and w+4 (3 loads)
  #define STAGE_QKV(b, k0)                                                        \
    do {                                                                          \
      glds16(A + (size_t)(m0 + 16*wave + lr) * K + (k0) + lcs,                    \
             (char*)&As[b][0][0] + wave*1024);                                    \
      glds16(Bb + (size_t)(16*wave + lr) * K + (k0) + lcs,                        \
             (char*)&Bs[b][0][0] + wave*1024);                                    \
      glds16(Bb + (size_t)(64 + 16*wave + lr) * K + (k0) + lcs,                   \
             (char*)&Bs[b][0][0] + (4+wave)*1024);                                \
    } while (0)

  const int NT = K / 32;             // 64
  STAGE_QKV(0, 0);
  STAGE_QKV(1, 32);
  STAGE_QKV(2, 64);
  for (int t = 0; t < NT; ++t) {
    // outstanding at top: tiles t, t+1, t+2 (9 loads) -> vmcnt(6) completes
    // tile t.  Tail: fewer outstanding -> tighter counts.
    if      (t < NT - 2) wait_vm6();
    else if (t == NT - 2) wait_vm3();
    else                  wait_vm0();
    raw_barrier();                   // all waves: tile t visible AND tile t-1
    mem_pin();                       // fully read (during iter t-1)
    if (t + 3 < NT) STAGE_QKV((t + 3) & 3, (t + 3) * 32);  // overwrite t-1 slot
    const int cur = t & 3;
    bf16x8 af[2], bfr[4];
    #pragma unroll
    for (int i = 0; i < 2; i++) af[i]  = *(const bf16x8*)&As[cur][wm + i*16 + l16][rc];
    #pragma unroll
    for (int j = 0; j < 4; j++) bfr[j] = *(const bf16x8*)&Bs[cur][wn + j*16 + l16][rc];
    #pragma unroll
    for (int i = 0; i < 2; i++)
      #pragma unroll
      for (int j = 0; j < 4; j++)
        acc[i][j] = __builtin_amdgcn_mfma_f32_16x16x32_bf16(af[i], bfr[j], acc[i][j], 0, 0, 0);
    mem_pin();
  }
  #undef STAGE_QKV

  if (mode == 0) {                   // ---- Q: plain bf16 store ----
    #pragma unroll
    for (int i = 0; i < 2; i++) {
      const int rb = m0 + wm + i*16 + quad*4;
      #pragma unroll
      for (int j = 0; j < 4; j++) {
        const int col = nc0 + wn + j*16 + l16;
        #pragma unroll
        for (int r = 0; r < 4; r++)
          Qb[(size_t)(rb + r) * QN + col] = f2bf(acc[i][j][r]);
      }
    }
  } else if (mode == 1) {            // ---- K: fused RoPE (f32, pre-round) ----
    const int hc = nc0 + wn;         // head col base (multiple of 64)
    #pragma unroll
    for (int i = 0; i < 2; i++) {
      const int rb = m0 + wm + i*16 + quad*4;
      #pragma unroll
      for (int j = 0; j < 2; j++) {
        const int d = j*16 + l16;    // 0..31; partner at d+32 is acc[i][j+2]
        #pragma unroll
        for (int r = 0; r < 4; r++) {
          const int s = rb + r;
          const float c  = bf2f(cosb[s*64 + d]);
          const float sn = bf2f(sinb[s*64 + d]);
          const float x1 = acc[i][j][r], x2 = acc[i][j+2][r];
          Kb[(size_t)s * KVNN + hc + d]      = f2bf(x1*c - x2*sn);
          Kb[(size_t)s * KVNN + hc + d + 32] = f2bf(x2*c + x1*sn);
        }
      }
    }
  } else {                           // ---- V: fused transpose into Vtg ----
    const int hkv = (nc0 + wn) >> 6;
    #pragma unroll
    for (int i = 0; i < 2; i++) {
      const int sbase = m0 + wm + i*16 + quad*4;
      #pragma unroll
      for (int j = 0; j < 4; j++) {
        const int d = j*16 + l16;
        union { u16 h[4]; uint2 v; } ok;
        #pragma unroll
        for (int r = 0; r < 4; r++) ok.h[r] = f2bf(acc[i][j][r]);
        *(uint2*)(Vtg + (size_t)(hkv*64 + d) * SEQ + sbase) = ok.v;
      }
    }
  }
}

// ---------------------------------------------------------------------------
// O-projection GEMM, quad-buffered 1-barrier pipeline + T2 swizzle.
// Grid 16 x 32 = 512 blocks.
// ---------------------------------------------------------------------------
__global__ __launch_bounds__(256, 4)
void gemm_nt(const u16* __restrict__ A, const u16* __restrict__ B,
             void* __restrict__ C, int M, int N, int K,
             const uint32_t* outprobe)
{
  __shared__ __align__(16) u16 As[4][64][32];
  __shared__ __align__(16) u16 Bs[4][128][32];
  const int tid  = threadIdx.x;
  const int wave = tid >> 6;
  const int lane = tid & 63;
  const int quad = lane >> 4;
  const int l16  = lane & 15;
  const int m0 = blockIdx.y * 64;
  const int n0 = blockIdx.x * 128;
  const int wm = (wave & 1) * 32;
  const int wn = (wave >> 1) * 64;
  const int lr = lane >> 2;
  const int lcs = (((lane & 3) ^ ((lr >> 1) & 3)) * 8);
  const int rc  = (quad ^ ((l16 >> 1) & 3)) * 8;

  f32x4 acc[2][4];
  #pragma unroll
  for (int i = 0; i < 2; i++)
    #pragma unroll
    for (int j = 0; j < 4; j++)
      acc[i][j] = (f32x4){0.f, 0.f, 0.f, 0.f};

  #define STAGE_NT(b, k0)                                                         \
    do {                                                                          \
      glds16(A + (size_t)(m0 + 16*wave + lr) * K + (k0) + lcs,                    \
             (char*)&As[b][0][0] + wave*1024);                                    \
      glds16(B + (size_t)(n0 + 16*wave + lr) * K + (k0) + lcs,                    \
             (char*)&Bs[b][0][0] + wave*1024);                                    \
      glds16(B + (size_t)(n0 + 64 + 16*wave + lr) * K + (k0) + lcs,               \
             (char*)&Bs[b][0][0] + (4+wave)*1024);                                \
    } while (0)

  const int NT = K / 32;
  STAGE_NT(0, 0);
  STAGE_NT(1, 32);
  STAGE_NT(2, 64);
  for (int t = 0; t < NT; ++t) {
    if      (t < NT - 2) wait_vm6();
    else if (t == NT - 2) wait_vm3();
    else                  wait_vm0();
    raw_barrier();
    mem_pin();
    if (t + 3 < NT) STAGE_NT((t + 3) & 3, (t + 3) * 32);
    const int cur = t & 3;
    bf16x8 af[2], bfr[4];
    #pragma unroll
    for (int i = 0; i < 2; i++) af[i]  = *(const bf16x8*)&As[cur][wm + i*16 + l16][rc];
    #pragma unroll
    for (int j = 0; j < 4; j++) bfr[j] = *(const bf16x8*)&Bs[cur][wn + j*16 + l16][rc];
    #pragma unroll
    for (int i = 0; i < 2; i++)
      #pragma unroll
      for (int j = 0; j < 4; j++)
        acc[i][j] = __builtin_amdgcn_mfma_f32_16x16x32_bf16(af[i], bfr[j], acc[i][j], 0, 0, 0);
    mem_pin();
  }
  #undef STAGE_NT

  const bool f32out = (outprobe != nullptr) && probe_is_f32(outprobe);
  #pragma unroll
  for (int i = 0; i < 2; i++) {
    const int rb = m0 + wm + i*16 + quad*4;
    #pragma unroll
    for (int j = 0; j < 4; j++) {
      const int col = n0 + wn + j*16 + l16;
      if (f32out) {
        float* Cf = (float*)C;
        #pragma unroll
        for (int r = 0; r < 4; r++)
          Cf[(size_t)(rb + r) * N + col] = acc[i][j][r];
      } else {
        u16* Ch = (u16*)C;
        #pragma unroll
        for (int r = 0; r < 4; r++)
          Ch[(size_t)(rb + r) * N + col] = f2bf(acc[i][j][r]);
      }
    }
  }
}

// ---------------------------------------------------------------------------
// Causal GQA flash attention v9 (round-8/10/11/12 proven, unchanged):
// operand-swapped MFMAs, lane-local softmax, exp2 domain, packed stores.
// ---------------------------------------------------------------------------
#define LOG2E 1.4426950408889634f

__global__ __launch_bounds__(256, 4)
void attn_kernel(const u16* __restrict__ Qb,   // [SEQ][2048] pre-rope
                 const u16* __restrict__ Kb,   // [SEQ][512]  RoPE'd
                 const u16* __restrict__ Vtg,  // [8][64][SEQ]
                 u16* __restrict__ Ob,         // [SEQ][2048]
                 const u16* __restrict__ cosb, const u16* __restrict__ sinb)
{
  __shared__ __align__(16) u16 Ks[64][72];     // [key][d]
  __shared__ __align__(16) u16 Vt[64][72];     // [d][key]
  __shared__ __align__(16) u16 Ps[4][16][72];  // per-wave P round-trip [query][key]

  const int tid  = threadIdx.x;
  const int wave = tid >> 6;
  const int lane = tid & 63;
  const int quad = lane >> 4;
  const int l16  = lane & 15;
  const int h    = blockIdx.x;                 // 0..31
  const int qt   = 31 - blockIdx.y;            // heavy 64-row tiles first
  const int hkv  = h >> 2;
  const int qrow0 = qt * 64 + wave * 16;
  const int ktmax = qt + 1;
  const int myq  = qrow0 + l16;                // this lane's query row

  // ---- one-time Q load + fused RoPE + 1/8 scale (A/B-layout frags) ----
  bf16x8 qf[2];
  {
    const int qrow = qrow0 + l16;
    const u16* qp = Qb + (size_t)qrow * QN + h*64 + quad*8;
    union { bf16x8 v; u16 h8[8]; } lo, hi, cv, sv, olo, ohi;
    lo.v = *(const bf16x8*)qp;
    hi.v = *(const bf16x8*)(qp + 32);
    cv.v = *(const bf16x8*)(cosb + qrow*64 + quad*8);   // cos[d+32]==cos[d]
    sv.v = *(const bf16x8*)(sinb + qrow*64 + quad*8);
    #pragma unroll
    for (int j = 0; j < 8; j++) {
      const float x1 = bf2f(lo.h8[j]), x2 = bf2f(hi.h8[j]);
      const float c = bf2f(cv.h8[j]), sn = bf2f(sv.h8[j]);
      olo.h8[j] = f2bf((x1*c - x2*sn) * 0.125f);
      ohi.h8[j] = f2bf((x2*c + x1*sn) * 0.125f);
    }
    qf[0] = olo.v;
    qf[1] = ohi.v;
  }

  // oacc[nt][r]: d = nt*16 + quad*4 + r, query = l16 (lane-local!)
  f32x4 oacc[4];
  #pragma unroll
  for (int nt = 0; nt < 4; nt++) oacc[nt] = (f32x4){0.f, 0.f, 0.f, 0.f};
  float m_run = -1e30f, l_run = 0.f;           // per-lane (query = myq)

  const int sr = tid >> 3;          // 0..31
  const int sc = (tid & 7) * 8;     // 0..56

  // ---- register prefetch of tile 0 ----
  uint4 k0, k1, v0, v1;
  {
    k0 = *(const uint4*)(Kb + (size_t)(sr)      * KVNN + hkv*64 + sc);
    k1 = *(const uint4*)(Kb + (size_t)(sr + 32) * KVNN + hkv*64 + sc);
    v0 = *(const uint4*)(Vtg + (size_t)(hkv*64 + sr)      * SEQ + sc);
    v1 = *(const uint4*)(Vtg + (size_t)(hkv*64 + sr + 32) * SEQ + sc);
  }

  for (int kt = 0; kt < ktmax; kt++) {
    const int kb = kt * 64;
    const bool diag = (kt == qt);

    __syncthreads();                 // all waves done reading LDS (prev iter)
    *(uint4*)&Ks[sr][sc]      = k0;
    *(uint4*)&Ks[sr + 32][sc] = k1;
    *(uint4*)&Vt[sr][sc]      = v0;  // Vt row = d, col = key (pre-transposed)
    *(uint4*)&Vt[sr + 32][sc] = v1;
    __syncthreads();

    // ---- issue next tile's staging loads (latency hides behind compute) ----
    if (kt + 1 < ktmax) {
      const int kn = kb + 64;
      k0 = *(const uint4*)(Kb + (size_t)(kn + sr)      * KVNN + hkv*64 + sc);
      k1 = *(const uint4*)(Kb + (size_t)(kn + sr + 32) * KVNN + hkv*64 + sc);
      v0 = *(const uint4*)(Vtg + (size_t)(hkv*64 + sr)      * SEQ + kn + sc);
      v1 = *(const uint4*)(Vtg + (size_t)(hkv*64 + sr + 32) * SEQ + kn + sc);
    }

    // ---- S = K @ Q^T (swapped): sacc[nt][r] = S[key=kb+nt*16+quad*4+r][myq]
    f32x4 sacc[4];
    #pragma unroll
    for (int nt = 0; nt < 4; nt++) sacc[nt] = (f32x4){0.f, 0.f, 0.f, 0.f};
    #pragma unroll
    for (int ks = 0; ks < 2; ks++)
      #pragma unroll
      for (int nt = 0; nt < 4; nt++)
        if (!diag || nt <= wave) {
          bf16x8 kf = *(const bf16x8*)&Ks[nt*16 + l16][ks*32 + quad*8];
          sacc[nt] = __builtin_amdgcn_mfma_f32_16x16x32_bf16(kf, qf[ks], sacc[nt], 0, 0, 0);
        }
    // ---- to log2 domain ----
    #pragma unroll
    for (int nt = 0; nt < 4; nt++)
      #pragma unroll
      for (int r = 0; r < 4; r++)
        sacc[nt][r] *= LOG2E;
    // ---- causal mask (diagonal tile only): key > query ----
    if (diag) {
      #pragma unroll
      for (int nt = 0; nt < 4; nt++)
        #pragma unroll
        for (int r = 0; r < 4; r++)
          if (kb + nt*16 + quad*4 + r > myq)
            sacc[nt][r] = -1e30f;
    }
    // ---- online softmax: in-lane over 16 + 2 shfl across quads ----
    float mx = sacc[0][0];
    #pragma unroll
    for (int nt = 0; nt < 4; nt++)
      #pragma unroll
      for (int r = 0; r < 4; r++)
        if (nt | r) mx = fmaxf(mx, sacc[nt][r]);
    mx = fmaxf(mx, __shfl_xor(mx, 16));
    mx = fmaxf(mx, __shfl_xor(mx, 32));
    const float mnew = fmaxf(m_run, mx);
    const float alpha = fexp2(m_run - mnew);
    m_run = mnew;
    float rs = 0.f;
    #pragma unroll
    for (int nt = 0; nt < 4; nt++)
      #pragma unroll
      for (int r = 0; r < 4; r++) {
        const float p = fexp2(sacc[nt][r] - mnew);
        sacc[nt][r] = p;
        rs += p;
      }
    rs += __shfl_xor(rs, 16);
    rs += __shfl_xor(rs, 32);
    l_run = l_run * alpha + rs;
    // ---- write P packed (4 keys per b64): Ps[wave][query][key] ----
    #pragma unroll
    for (int nt = 0; nt < 4; nt++) {
      union { u16 h[4]; uint2 v; } pk;
      #pragma unroll
      for (int r = 0; r < 4; r++) pk.h[r] = f2bf(sacc[nt][r]);
      *(uint2*)&Ps[wave][l16][nt*16 + quad*4] = pk.v;
    }
    // ---- rescale O (alpha is lane-local) ----
    #pragma unroll
    for (int nt = 0; nt < 4; nt++)
      #pragma unroll
      for (int r = 0; r < 4; r++)
        oacc[nt][r] *= alpha;
    // keep Ps vector loads below the stores (wave-private, in-order)
    asm volatile("" ::: "memory");
    // ---- O += V @ P^T (swapped): out rows = d, cols = query ----
    #pragma unroll
    for (int ks = 0; ks < 2; ks++) {
      if (diag && wave < 2 && ks == 1) continue;  // keys 32..63 fully masked
      bf16x8 pf = *(const bf16x8*)&Ps[wave][l16][ks*32 + quad*8];
      #pragma unroll
      for (int nt = 0; nt < 4; nt++) {
        bf16x8 vf = *(const bf16x8*)&Vt[nt*16 + l16][ks*32 + quad*8];
        oacc[nt] = __builtin_amdgcn_mfma_f32_16x16x32_bf16(vf, pf, oacc[nt], 0, 0, 0);
      }
    }
  }

  // ---- epilogue (lane-local inv; packed 8B stores) ----
  {
    const float inv = 1.0f / l_run;
    #pragma unroll
    for (int nt = 0; nt < 4; nt++) {
      union { u16 h[4]; uint2 v; } ok;
      #pragma unroll
      for (int r = 0; r < 4; r++) ok.h[r] = f2bf(oacc[nt][r] * inv);
      *(uint2*)(Ob + (size_t)myq * QN + h*64 + nt*16 + quad*4) = ok.v;
    }
  }
}

// ---------------------------------------------------------------------------
extern "C" void kernel_launch(void* const* d_in, const int* in_sizes, int n_in,
                              void* d_out, int out_size, void* d_ws, size_t ws_size,
                              hipStream_t stream) {
  const void* X    = d_in[0];
  const void* cosr = d_in[1];
  const void* sinr = d_in[2];
  const void* wq   = d_in[3];
  const void* wk   = d_in[4];
  const void* wv   = d_in[5];
  const void* wo   = d_in[6];

  char* ws = (char*)d_ws;
  const size_t MB = 1024u * 1024u;
  u16* Xc   = (u16*)(ws);                      // 8 MB
  u16* wqc  = (u16*)(ws + 8*MB);               // 8 MB (Ab aliases after QKV gemm)
  u16* wkc  = (u16*)(ws + 16*MB);              // 2 MB
  u16* wvc  = (u16*)(ws + 18*MB);              // 2 MB
  u16* woc  = (u16*)(ws + 20*MB);              // 8 MB
  u16* cosc = (u16*)(ws + 28*MB);              // 256 KB
  u16* sinc = (u16*)(ws + 28*MB + 256*1024);   // 256 KB
  u16* Qb   = (u16*)(ws + 28*MB + 512*1024);   // 8 MB
  u16* Kb   = (u16*)(ws + 36*MB + 512*1024);   // 2 MB
  u16* Vtg  = (u16*)(ws + 40*MB + 512*1024);   // 2 MB (written by gemm_qkv)
  u16* Ab   = wqc;   // wqc dead after gemm_qkv

  dim3 b256(256);
  conv_all<<<dim3(7296), b256, 0, stream>>>(X, cosr, sinr, wq, wk, wv, wo,
                                            Xc, cosc, sinc, wqc, wkc, wvc, woc);
  gemm_qkv<<<dim3(24, 32), b256, 0, stream>>>(Xc, wqc, wkc, wvc, Qb, Kb, Vtg,
                                              cosc, sinc);
  attn_kernel<<<dim3(NQH, SEQ/64), b256, 0, stream>>>(Qb, Kb, Vtg, Ab, cosc, sinc);
  gemm_nt<<<dim3(16, 32), b256, 0, stream>>>(Ab, woc, d_out, SEQ, DMODEL, DMODEL,
                                             (const uint32_t*)cosr);
}

// Round 14
// 221.857 us; speedup vs baseline: 1.0078x; 1.0078x over previous
//
#include <hip/hip_runtime.h>
#include <stdint.h>

#define SEQ   2048
#define DMODEL 2048
#define NQH   32
#define NKVH  8
#define HDIM  64
#define QN    (NQH*HDIM)    // 2048
#define KVNN  (NKVH*HDIM)   // 512

typedef __bf16 bf16x8 __attribute__((ext_vector_type(8)));
typedef float  f32x4  __attribute__((ext_vector_type(4)));
typedef unsigned short u16;

// f32 -> bf16 RNE via native cast: compiler emits the hardware cvt.
__device__ __forceinline__ u16 f2bf(float f) {
  __bf16 h = (__bf16)f;
  return __builtin_bit_cast(u16, h);
}
__device__ __forceinline__ float bf2f(u16 b) {
  return __builtin_bit_cast(float, (uint32_t)b << 16);
}
__device__ __forceinline__ float fexp2(float x) {
#if __has_builtin(__builtin_amdgcn_exp2f)
  return __builtin_amdgcn_exp2f(x);   // bare v_exp_f32
#else
  return __expf(0.69314718056f * x);  // hazard-safe fallback
#endif
}
__device__ __forceinline__ bool probe_is_f32(const uint32_t* p) {
  return (p[0] & 0xFFFFu) == 0u;   // cos[0]=1.0: f32->0x3F800000, bf16 pair->0x3F803F80
}

// global -> LDS direct DMA, 16B per lane, LDS dest = uniform base + lane*16
__device__ __forceinline__ void glds16(const u16* g, void* lds) {
  __builtin_amdgcn_global_load_lds(
      (const __attribute__((address_space(1))) uint32_t*)g,
      (__attribute__((address_space(3))) uint32_t*)lds, 16, 0, 0);
}
// Counted vmem waits (T4) + raw barrier (round-12 proven GEMM pipeline).
__device__ __forceinline__ void wait_vm6() { asm volatile("s_waitcnt vmcnt(6)" ::: "memory"); }
__device__ __forceinline__ void wait_vm3() { asm volatile("s_waitcnt vmcnt(3)" ::: "memory"); }
__device__ __forceinline__ void wait_vm0() { asm volatile("s_waitcnt vmcnt(0)" ::: "memory"); }
__device__ __forceinline__ void raw_barrier() { __builtin_amdgcn_s_barrier(); }
__device__ __forceinline__ void mem_pin() { asm volatile("" ::: "memory"); }

// ---------------------------------------------------------------------------
// Fused input conversion: all 7 inputs -> bf16 copies in ws (8 elts/thread).
// ---------------------------------------------------------------------------
__global__ __launch_bounds__(256)
void conv_all(const void* __restrict__ X, const void* __restrict__ cosv,
              const void* __restrict__ sinv, const void* __restrict__ wq,
              const void* __restrict__ wk, const void* __restrict__ wv,
              const void* __restrict__ wo,
              u16* __restrict__ Xc, u16* __restrict__ cosc, u16* __restrict__ sinc,
              u16* __restrict__ wqc, u16* __restrict__ wkc, u16* __restrict__ wvc,
              u16* __restrict__ woc)
{
  const bool f32in = probe_is_f32((const uint32_t*)cosv);
  const long t = (long)blockIdx.x * 256 + threadIdx.x;
  const void* src; u16* dst; long off;
  if      (t < 524288L)  { src = X;    dst = Xc;   off = t; }
  else if (t < 1048576L) { src = wq;   dst = wqc;  off = t - 524288L; }
  else if (t < 1179648L) { src = wk;   dst = wkc;  off = t - 1048576L; }
  else if (t < 1310720L) { src = wv;   dst = wvc;  off = t - 1179648L; }
  else if (t < 1835008L) { src = wo;   dst = woc;  off = t - 1310720L; }
  else if (t < 1851392L) { src = cosv; dst = cosc; off = t - 1835008L; }
  else                   { src = sinv; dst = sinc; off = t - 1851392L; }
  if (f32in) {
    const float4* s = (const float4*)src;
    float4 a = s[2*off], b = s[2*off + 1];
    union { u16 h[8]; uint4 u; } o;
    o.h[0]=f2bf(a.x); o.h[1]=f2bf(a.y); o.h[2]=f2bf(a.z); o.h[3]=f2bf(a.w);
    o.h[4]=f2bf(b.x); o.h[5]=f2bf(b.y); o.h[6]=f2bf(b.z); o.h[7]=f2bf(b.w);
    *(uint4*)(dst + off*8) = o.u;
  } else {
    *(uint4*)(dst + off*8) = ((const uint4*)src)[off];
  }
}

// ---------------------------------------------------------------------------
// Merged QKV projection, 64m x 128n tiles, 4 waves/block, triple-buffered
// global_load_lds, counted vmcnt + raw s_barrier (round-12 best, 221.1us) +
// T2 bank swizzle (conflicts=0) + fused RoPE-K / V-transpose epilogues +
// NEW: T1 XCD-aware bijective block swizzle (each XCD's L2 sees only 4
// A-panels = 1 MB instead of ~all of A; FETCH 40MB showed ~4x A re-fetch)
// + T5 setprio around the MFMA cluster.  Grid 24 x 32 = 768 blocks (3/CU).
// ---------------------------------------------------------------------------
__global__ __launch_bounds__(256, 4)
void gemm_qkv(const u16* __restrict__ A,
              const u16* __restrict__ wq, const u16* __restrict__ wk,
              const u16* __restrict__ wv,
              u16* __restrict__ Qb, u16* __restrict__ Kb, u16* __restrict__ Vtg,
              const u16* __restrict__ cosb, const u16* __restrict__ sinb)
{
  __shared__ __align__(16) u16 As[3][64][32];    // 12 KB
  __shared__ __align__(16) u16 Bs[3][128][32];   // 24 KB
  const int tid  = threadIdx.x;
  const int wave = tid >> 6;
  const int lane = tid & 63;
  const int quad = lane >> 4;
  const int l16  = lane & 15;
  // T1: hardware round-robins linear block id over 8 XCDs; remap so XCD k
  // owns contiguous logical chunk [96k, 96(k+1)) = 4 m-rows x all 24 n-tiles.
  const int lin = blockIdx.y * 24 + blockIdx.x;       // 0..767
  const int swz = (lin & 7) * 96 + (lin >> 3);
  const int m0 = (swz / 24) * 64;
  const int n0 = (swz % 24) * 128;
  const int K = DMODEL;
  const int lr = lane >> 2;                      // 0..15 row within chunk
  const int lcs = (((lane & 3) ^ ((lr >> 1) & 3)) * 8);  // swizzled src col
  const int rc  = (quad ^ ((l16 >> 1) & 3)) * 8;         // swizzled read col
  const int wm = (wave & 1) * 32;
  const int wn = (wave >> 1) * 64;

  const u16* Bb; int mode, nc0;      // 0=Q, 1=K(rope), 2=V(transpose)
  if (n0 < 2048)      { Bb = wq + (size_t)n0 * K;          mode = 0; nc0 = n0; }
  else if (n0 < 2560) { Bb = wk + (size_t)(n0 - 2048) * K; mode = 1; nc0 = n0 - 2048; }
  else                { Bb = wv + (size_t)(n0 - 2560) * K; mode = 2; nc0 = n0 - 2560; }

  f32x4 acc[2][4];
  #pragma unroll
  for (int i = 0; i < 2; i++)
    #pragma unroll
    for (int j = 0; j < 4; j++)
      acc[i][j] = (f32x4){0.f, 0.f, 0.f, 0.f};

  // wave w stages: A chunk w (rows 16w..16w+15), B chunks w and w+4 (3 loads)
  #define STAGE_QKV(b, k0)                                                        \
    do {                                                                          \
      glds16(A + (size_t)(m0 + 16*wave + lr) * K + (k0) + lcs,                    \
             (char*)&As[b][0][0] + wave*1024);                                    \
      glds16(Bb + (size_t)(16*wave + lr) * K + (k0) + lcs,                        \
             (char*)&Bs[b][0][0] + wave*1024);                                    \
      glds16(Bb + (size_t)(64 + 16*wave + lr) * K + (k0) + lcs,                   \
             (char*)&Bs[b][0][0] + (4+wave)*1024);                                \
    } while (0)

  const int NT = K / 32;             // 64
  STAGE_QKV(0, 0);
  STAGE_QKV(1, 32);
  STAGE_QKV(2, 64);
  int cur = 0;
  for (int t = 0; t < NT; ++t) {
    if      (t < NT - 2) wait_vm6();
    else if (t == NT - 2) wait_vm3();
    else                  wait_vm0();
    raw_barrier();                   // all waves' tile-t data visible
    mem_pin();
    bf16x8 af[2], bfr[4];
    #pragma unroll
    for (int i = 0; i < 2; i++) af[i]  = *(const bf16x8*)&As[cur][wm + i*16 + l16][rc];
    #pragma unroll
    for (int j = 0; j < 4; j++) bfr[j] = *(const bf16x8*)&Bs[cur][wn + j*16 + l16][rc];
    __builtin_amdgcn_s_setprio(1);
    #pragma unroll
    for (int i = 0; i < 2; i++)
      #pragma unroll
      for (int j = 0; j < 4; j++)
        acc[i][j] = __builtin_amdgcn_mfma_f32_16x16x32_bf16(af[i], bfr[j], acc[i][j], 0, 0, 0);
    __builtin_amdgcn_s_setprio(0);
    raw_barrier();                   // all waves' reads of buf[cur] done
    mem_pin();
    if (t + 3 < NT) STAGE_QKV(cur, (t + 3) * 32);
    cur = (cur == 2) ? 0 : cur + 1;
  }
  #undef STAGE_QKV

  if (mode == 0) {                   // ---- Q: plain bf16 store ----
    #pragma unroll
    for (int i = 0; i < 2; i++) {
      const int rb = m0 + wm + i*16 + quad*4;
      #pragma unroll
      for (int j = 0; j < 4; j++) {
        const int col = nc0 + wn + j*16 + l16;
        #pragma unroll
        for (int r = 0; r < 4; r++)
          Qb[(size_t)(rb + r) * QN + col] = f2bf(acc[i][j][r]);
      }
    }
  } else if (mode == 1) {            // ---- K: fused RoPE (f32, pre-round) ----
    const int hc = nc0 + wn;         // head col base (multiple of 64)
    #pragma unroll
    for (int i = 0; i < 2; i++) {
      const int rb = m0 + wm + i*16 + quad*4;
      #pragma unroll
      for (int j = 0; j < 2; j++) {
        const int d = j*16 + l16;    // 0..31; partner at d+32 is acc[i][j+2]
        #pragma unroll
        for (int r = 0; r < 4; r++) {
          const int s = rb + r;
          const float c  = bf2f(cosb[s*64 + d]);
          const float sn = bf2f(sinb[s*64 + d]);
          const float x1 = acc[i][j][r], x2 = acc[i][j+2][r];
          Kb[(size_t)s * KVNN + hc + d]      = f2bf(x1*c - x2*sn);
          Kb[(size_t)s * KVNN + hc + d + 32] = f2bf(x2*c + x1*sn);
        }
      }
    }
  } else {                           // ---- V: fused transpose into Vtg ----
    const int hkv = (nc0 + wn) >> 6;
    #pragma unroll
    for (int i = 0; i < 2; i++) {
      const int sbase = m0 + wm + i*16 + quad*4;
      #pragma unroll
      for (int j = 0; j < 4; j++) {
        const int d = j*16 + l16;
        union { u16 h[4]; uint2 v; } ok;
        #pragma unroll
        for (int r = 0; r < 4; r++) ok.h[r] = f2bf(acc[i][j][r]);
        *(uint2*)(Vtg + (size_t)(hkv*64 + d) * SEQ + sbase) = ok.v;
      }
    }
  }
}

// ---------------------------------------------------------------------------
// O-projection GEMM, triple-buffered counted-vmcnt + raw s_barrier + T2
// swizzle + T1 XCD block swizzle + T5 setprio. Grid 16 x 32 = 512 blocks.
// ---------------------------------------------------------------------------
__global__ __launch_bounds__(256, 4)
void gemm_nt(const u16* __restrict__ A, const u16* __restrict__ B,
             void* __restrict__ C, int M, int N, int K,
             const uint32_t* outprobe)
{
  __shared__ __align__(16) u16 As[3][64][32];
  __shared__ __align__(16) u16 Bs[3][128][32];
  const int tid  = threadIdx.x;
  const int wave = tid >> 6;
  const int lane = tid & 63;
  const int quad = lane >> 4;
  const int l16  = lane & 15;
  const int lin = blockIdx.y * 16 + blockIdx.x;       // 0..511
  const int swz = (lin & 7) * 64 + (lin >> 3);
  const int m0 = (swz / 16) * 64;
  const int n0 = (swz % 16) * 128;
  const int wm = (wave & 1) * 32;
  const int wn = (wave >> 1) * 64;
  const int lr = lane >> 2;
  const int lcs = (((lane & 3) ^ ((lr >> 1) & 3)) * 8);
  const int rc  = (quad ^ ((l16 >> 1) & 3)) * 8;

  f32x4 acc[2][4];
  #pragma unroll
  for (int i = 0; i < 2; i++)
    #pragma unroll
    for (int j = 0; j < 4; j++)
      acc[i][j] = (f32x4){0.f, 0.f, 0.f, 0.f};

  #define STAGE_NT(b, k0)                                                         \
    do {                                                                          \
      glds16(A + (size_t)(m0 + 16*wave + lr) * K + (k0) + lcs,                    \
             (char*)&As[b][0][0] + wave*1024);                                    \
      glds16(B + (size_t)(n0 + 16*wave + lr) * K + (k0) + lcs,                    \
             (char*)&Bs[b][0][0] + wave*1024);                                    \
      glds16(B + (size_t)(n0 + 64 + 16*wave + lr) * K + (k0) + lcs,               \
             (char*)&Bs[b][0][0] + (4+wave)*1024);                                \
    } while (0)

  const int NT = K / 32;
  STAGE_NT(0, 0);
  STAGE_NT(1, 32);
  STAGE_NT(2, 64);
  int cur = 0;
  for (int t = 0; t < NT; ++t) {
    if      (t < NT - 2) wait_vm6();
    else if (t == NT - 2) wait_vm3();
    else                  wait_vm0();
    raw_barrier();
    mem_pin();
    bf16x8 af[2], bfr[4];
    #pragma unroll
    for (int i = 0; i < 2; i++) af[i]  = *(const bf16x8*)&As[cur][wm + i*16 + l16][rc];
    #pragma unroll
    for (int j = 0; j < 4; j++) bfr[j] = *(const bf16x8*)&Bs[cur][wn + j*16 + l16][rc];
    __builtin_amdgcn_s_setprio(1);
    #pragma unroll
    for (int i = 0; i < 2; i++)
      #pragma unroll
      for (int j = 0; j < 4; j++)
        acc[i][j] = __builtin_amdgcn_mfma_f32_16x16x32_bf16(af[i], bfr[j], acc[i][j], 0, 0, 0);
    __builtin_amdgcn_s_setprio(0);
    raw_barrier();
    mem_pin();
    if (t + 3 < NT) STAGE_NT(cur, (t + 3) * 32);
    cur = (cur == 2) ? 0 : cur + 1;
  }
  #undef STAGE_NT

  const bool f32out = (outprobe != nullptr) && probe_is_f32(outprobe);
  #pragma unroll
  for (int i = 0; i < 2; i++) {
    const int rb = m0 + wm + i*16 + quad*4;
    #pragma unroll
    for (int j = 0; j < 4; j++) {
      const int col = n0 + wn + j*16 + l16;
      if (f32out) {
        float* Cf = (float*)C;
        #pragma unroll
        for (int r = 0; r < 4; r++)
          Cf[(size_t)(rb + r) * N + col] = acc[i][j][r];
      } else {
        u16* Ch = (u16*)C;
        #pragma unroll
        for (int r = 0; r < 4; r++)
          Ch[(size_t)(rb + r) * N + col] = f2bf(acc[i][j][r]);
      }
    }
  }
}

// ---------------------------------------------------------------------------
// Causal GQA flash attention v9 (round-8/10/11/12 proven, unchanged):
// operand-swapped MFMAs, lane-local softmax, exp2 domain, packed stores.
// ---------------------------------------------------------------------------
#define LOG2E 1.4426950408889634f

__global__ __launch_bounds__(256, 4)
void attn_kernel(const u16* __restrict__ Qb,   // [SEQ][2048] pre-rope
                 const u16* __restrict__ Kb,   // [SEQ][512]  RoPE'd
                 const u16* __restrict__ Vtg,  // [8][64][SEQ]
                 u16* __restrict__ Ob,         // [SEQ][2048]
                 const u16* __restrict__ cosb, const u16* __restrict__ sinb)
{
  __shared__ __align__(16) u16 Ks[64][72];     // [key][d]
  __shared__ __align__(16) u16 Vt[64][72];     // [d][key]
  __shared__ __align__(16) u16 Ps[4][16][72];  // per-wave P round-trip [query][key]

  const int tid  = threadIdx.x;
  const int wave = tid >> 6;
  const int lane = tid & 63;
  const int quad = lane >> 4;
  const int l16  = lane & 15;
  const int h    = blockIdx.x;                 // 0..31
  const int qt   = 31 - blockIdx.y;            // heavy 64-row tiles first
  const int hkv  = h >> 2;
  const int qrow0 = qt * 64 + wave * 16;
  const int ktmax = qt + 1;
  const int myq  = qrow0 + l16;                // this lane's query row

  // ---- one-time Q load + fused RoPE + 1/8 scale (A/B-layout frags) ----
  bf16x8 qf[2];
  {
    const int qrow = qrow0 + l16;
    const u16* qp = Qb + (size_t)qrow * QN + h*64 + quad*8;
    union { bf16x8 v; u16 h8[8]; } lo, hi, cv, sv, olo, ohi;
    lo.v = *(const bf16x8*)qp;
    hi.v = *(const bf16x8*)(qp + 32);
    cv.v = *(const bf16x8*)(cosb + qrow*64 + quad*8);   // cos[d+32]==cos[d]
    sv.v = *(const bf16x8*)(sinb + qrow*64 + quad*8);
    #pragma unroll
    for (int j = 0; j < 8; j++) {
      const float x1 = bf2f(lo.h8[j]), x2 = bf2f(hi.h8[j]);
      const float c = bf2f(cv.h8[j]), sn = bf2f(sv.h8[j]);
      olo.h8[j] = f2bf((x1*c - x2*sn) * 0.125f);
      ohi.h8[j] = f2bf((x2*c + x1*sn) * 0.125f);
    }
    qf[0] = olo.v;
    qf[1] = ohi.v;
  }

  // oacc[nt][r]: d = nt*16 + quad*4 + r, query = l16 (lane-local!)
  f32x4 oacc[4];
  #pragma unroll
  for (int nt = 0; nt < 4; nt++) oacc[nt] = (f32x4){0.f, 0.f, 0.f, 0.f};
  float m_run = -1e30f, l_run = 0.f;           // per-lane (query = myq)

  const int sr = tid >> 3;          // 0..31
  const int sc = (tid & 7) * 8;     // 0..56

  // ---- register prefetch of tile 0 ----
  uint4 k0, k1, v0, v1;
  {
    k0 = *(const uint4*)(Kb + (size_t)(sr)      * KVNN + hkv*64 + sc);
    k1 = *(const uint4*)(Kb + (size_t)(sr + 32) * KVNN + hkv*64 + sc);
    v0 = *(const uint4*)(Vtg + (size_t)(hkv*64 + sr)      * SEQ + sc);
    v1 = *(const uint4*)(Vtg + (size_t)(hkv*64 + sr + 32) * SEQ + sc);
  }

  for (int kt = 0; kt < ktmax; kt++) {
    const int kb = kt * 64;
    const bool diag = (kt == qt);

    __syncthreads();                 // all waves done reading LDS (prev iter)
    *(uint4*)&Ks[sr][sc]      = k0;
    *(uint4*)&Ks[sr + 32][sc] = k1;
    *(uint4*)&Vt[sr][sc]      = v0;  // Vt row = d, col = key (pre-transposed)
    *(uint4*)&Vt[sr + 32][sc] = v1;
    __syncthreads();

    // ---- issue next tile's staging loads (latency hides behind compute) ----
    if (kt + 1 < ktmax) {
      const int kn = kb + 64;
      k0 = *(const uint4*)(Kb + (size_t)(kn + sr)      * KVNN + hkv*64 + sc);
      k1 = *(const uint4*)(Kb + (size_t)(kn + sr + 32) * KVNN + hkv*64 + sc);
      v0 = *(const uint4*)(Vtg + (size_t)(hkv*64 + sr)      * SEQ + kn + sc);
      v1 = *(const uint4*)(Vtg + (size_t)(hkv*64 + sr + 32) * SEQ + kn + sc);
    }

    // ---- S = K @ Q^T (swapped): sacc[nt][r] = S[key=kb+nt*16+quad*4+r][myq]
    f32x4 sacc[4];
    #pragma unroll
    for (int nt = 0; nt < 4; nt++) sacc[nt] = (f32x4){0.f, 0.f, 0.f, 0.f};
    #pragma unroll
    for (int ks = 0; ks < 2; ks++)
      #pragma unroll
      for (int nt = 0; nt < 4; nt++)
        if (!diag || nt <= wave) {
          bf16x8 kf = *(const bf16x8*)&Ks[nt*16 + l16][ks*32 + quad*8];
          sacc[nt] = __builtin_amdgcn_mfma_f32_16x16x32_bf16(kf, qf[ks], sacc[nt], 0, 0, 0);
        }
    // ---- to log2 domain ----
    #pragma unroll
    for (int nt = 0; nt < 4; nt++)
      #pragma unroll
      for (int r = 0; r < 4; r++)
        sacc[nt][r] *= LOG2E;
    // ---- causal mask (diagonal tile only): key > query ----
    if (diag) {
      #pragma unroll
      for (int nt = 0; nt < 4; nt++)
        #pragma unroll
        for (int r = 0; r < 4; r++)
          if (kb + nt*16 + quad*4 + r > myq)
            sacc[nt][r] = -1e30f;
    }
    // ---- online softmax: in-lane over 16 + 2 shfl across quads ----
    float mx = sacc[0][0];
    #pragma unroll
    for (int nt = 0; nt < 4; nt++)
      #pragma unroll
      for (int r = 0; r < 4; r++)
        if (nt | r) mx = fmaxf(mx, sacc[nt][r]);
    mx = fmaxf(mx, __shfl_xor(mx, 16));
    mx = fmaxf(mx, __shfl_xor(mx, 32));
    const float mnew = fmaxf(m_run, mx);
    const float alpha = fexp2(m_run - mnew);
    m_run = mnew;
    float rs = 0.f;
    #pragma unroll
    for (int nt = 0; nt < 4; nt++)
      #pragma unroll
      for (int r = 0; r < 4; r++) {
        const float p = fexp2(sacc[nt][r] - mnew);
        sacc[nt][r] = p;
        rs += p;
      }
    rs += __shfl_xor(rs, 16);
    rs += __shfl_xor(rs, 32);
    l_run = l_run * alpha + rs;
    // ---- write P packed (4 keys per b64): Ps[wave][query][key] ----
    #pragma unroll
    for (int nt = 0; nt < 4; nt++) {
      union { u16 h[4]; uint2 v; } pk;
      #pragma unroll
      for (int r = 0; r < 4; r++) pk.h[r] = f2bf(sacc[nt][r]);
      *(uint2*)&Ps[wave][l16][nt*16 + quad*4] = pk.v;
    }
    // ---- rescale O (alpha is lane-local) ----
    #pragma unroll
    for (int nt = 0; nt < 4; nt++)
      #pragma unroll
      for (int r = 0; r < 4; r++)
        oacc[nt][r] *= alpha;
    // keep Ps vector loads below the stores (wave-private, in-order)
    asm volatile("" ::: "memory");
    // ---- O += V @ P^T (swapped): out rows = d, cols = query ----
    #pragma unroll
    for (int ks = 0; ks < 2; ks++) {
      if (diag && wave < 2 && ks == 1) continue;  // keys 32..63 fully masked
      bf16x8 pf = *(const bf16x8*)&Ps[wave][l16][ks*32 + quad*8];
      #pragma unroll
      for (int nt = 0; nt < 4; nt++) {
        bf16x8 vf = *(const bf16x8*)&Vt[nt*16 + l16][ks*32 + quad*8];
        oacc[nt] = __builtin_amdgcn_mfma_f32_16x16x32_bf16(vf, pf, oacc[nt], 0, 0, 0);
      }
    }
  }

  // ---- epilogue (lane-local inv; packed 8B stores) ----
  {
    const float inv = 1.0f / l_run;
    #pragma unroll
    for (int nt = 0; nt < 4; nt++) {
      union { u16 h[4]; uint2 v; } ok;
      #pragma unroll
      for (int r = 0; r < 4; r++) ok.h[r] = f2bf(oacc[nt][r] * inv);
      *(uint2*)(Ob + (size_t)myq * QN + h*64 + nt*16 + quad*4) = ok.v;
    }
  }
}

// ---------------------------------------------------------------------------
extern "C" void kernel_launch(void* const* d_in, const int* in_sizes, int n_in,
                              void* d_out, int out_size, void* d_ws, size_t ws_size,
                              hipStream_t stream) {
  const void* X    = d_in[0];
  const void* cosr = d_in[1];
  const void* sinr = d_in[2];
  const void* wq   = d_in[3];
  const void* wk   = d_in[4];
  const void* wv   = d_in[5];
  const void* wo   = d_in[6];

  char* ws = (char*)d_ws;
  const size_t MB = 1024u * 1024u;
  u16* Xc   = (u16*)(ws);                      // 8 MB
  u16* wqc  = (u16*)(ws + 8*MB);               // 8 MB (Ab aliases after QKV gemm)
  u16* wkc  = (u16*)(ws + 16*MB);              // 2 MB
  u16* wvc  = (u16*)(ws + 18*MB);              // 2 MB
  u16* woc  = (u16*)(ws + 20*MB);              // 8 MB
  u16* cosc = (u16*)(ws + 28*MB);              // 256 KB
  u16* sinc = (u16*)(ws + 28*MB + 256*1024);   // 256 KB
  u16* Qb   = (u16*)(ws + 28*MB + 512*1024);   // 8 MB
  u16* Kb   = (u16*)(ws + 36*MB + 512*1024);   // 2 MB
  u16* Vtg  = (u16*)(ws + 40*MB + 512*1024);   // 2 MB (written by gemm_qkv)
  u16* Ab   = wqc;   // wqc dead after gemm_qkv

  dim3 b256(256);
  conv_all<<<dim3(7296), b256, 0, stream>>>(X, cosr, sinr, wq, wk, wv, wo,
                                            Xc, cosc, sinc, wqc, wkc, wvc, woc);
  gemm_qkv<<<dim3(24, 32), b256, 0, stream>>>(Xc, wqc, wkc, wvc, Qb, Kb, Vtg,
                                              cosc, sinc);
  attn_kernel<<<dim3(NQH, SEQ/64), b256, 0, stream>>>(Qb, Kb, Vtg, Ab, cosc, sinc);
  gemm_nt<<<dim3(16, 32), b256, 0, stream>>>(Ab, woc, d_out, SEQ, DMODEL, DMODEL,
                                             (const uint32_t*)cosr);
}

// Round 15
// 219.235 us; speedup vs baseline: 1.0199x; 1.0120x over previous
//
#include <hip/hip_runtime.h>
#include <stdint.h>

#define SEQ   2048
#define DMODEL 2048
#define NQH   32
#define NKVH  8
#define HDIM  64
#define QN    (NQH*HDIM)    // 2048
#define KVNN  (NKVH*HDIM)   // 512

typedef __bf16 bf16x8 __attribute__((ext_vector_type(8)));
typedef float  f32x4  __attribute__((ext_vector_type(4)));
typedef unsigned short u16;

// f32 -> bf16 RNE via native cast: compiler emits the hardware cvt.
__device__ __forceinline__ u16 f2bf(float f) {
  __bf16 h = (__bf16)f;
  return __builtin_bit_cast(u16, h);
}
__device__ __forceinline__ float bf2f(u16 b) {
  return __builtin_bit_cast(float, (uint32_t)b << 16);
}
__device__ __forceinline__ float fexp2(float x) {
#if __has_builtin(__builtin_amdgcn_exp2f)
  return __builtin_amdgcn_exp2f(x);   // bare v_exp_f32
#else
  return __expf(0.69314718056f * x);  // hazard-safe fallback
#endif
}
__device__ __forceinline__ bool probe_is_f32(const uint32_t* p) {
  return (p[0] & 0xFFFFu) == 0u;   // cos[0]=1.0: f32->0x3F800000, bf16 pair->0x3F803F80
}

// global -> LDS direct DMA, 16B per lane, LDS dest = uniform base + lane*16
__device__ __forceinline__ void glds16(const u16* g, void* lds) {
  __builtin_amdgcn_global_load_lds(
      (const __attribute__((address_space(1))) uint32_t*)g,
      (__attribute__((address_space(3))) uint32_t*)lds, 16, 0, 0);
}
// Counted vmem waits (T4) + raw barrier (round-12 proven GEMM pipeline).
__device__ __forceinline__ void wait_vm6() { asm volatile("s_waitcnt vmcnt(6)" ::: "memory"); }
__device__ __forceinline__ void wait_vm3() { asm volatile("s_waitcnt vmcnt(3)" ::: "memory"); }
__device__ __forceinline__ void wait_vm0() { asm volatile("s_waitcnt vmcnt(0)" ::: "memory"); }
__device__ __forceinline__ void raw_barrier() { __builtin_amdgcn_s_barrier(); }
__device__ __forceinline__ void mem_pin() { asm volatile("" ::: "memory"); }

// ---------------------------------------------------------------------------
// Fused input conversion: all 7 inputs -> bf16 copies in ws (8 elts/thread).
// ---------------------------------------------------------------------------
__global__ __launch_bounds__(256)
void conv_all(const void* __restrict__ X, const void* __restrict__ cosv,
              const void* __restrict__ sinv, const void* __restrict__ wq,
              const void* __restrict__ wk, const void* __restrict__ wv,
              const void* __restrict__ wo,
              u16* __restrict__ Xc, u16* __restrict__ cosc, u16* __restrict__ sinc,
              u16* __restrict__ wqc, u16* __restrict__ wkc, u16* __restrict__ wvc,
              u16* __restrict__ woc)
{
  const bool f32in = probe_is_f32((const uint32_t*)cosv);
  const long t = (long)blockIdx.x * 256 + threadIdx.x;
  const void* src; u16* dst; long off;
  if      (t < 524288L)  { src = X;    dst = Xc;   off = t; }
  else if (t < 1048576L) { src = wq;   dst = wqc;  off = t - 524288L; }
  else if (t < 1179648L) { src = wk;   dst = wkc;  off = t - 1048576L; }
  else if (t < 1310720L) { src = wv;   dst = wvc;  off = t - 1179648L; }
  else if (t < 1835008L) { src = wo;   dst = woc;  off = t - 1310720L; }
  else if (t < 1851392L) { src = cosv; dst = cosc; off = t - 1835008L; }
  else                   { src = sinv; dst = sinc; off = t - 1851392L; }
  if (f32in) {
    const float4* s = (const float4*)src;
    float4 a = s[2*off], b = s[2*off + 1];
    union { u16 h[8]; uint4 u; } o;
    o.h[0]=f2bf(a.x); o.h[1]=f2bf(a.y); o.h[2]=f2bf(a.z); o.h[3]=f2bf(a.w);
    o.h[4]=f2bf(b.x); o.h[5]=f2bf(b.y); o.h[6]=f2bf(b.z); o.h[7]=f2bf(b.w);
    *(uint4*)(dst + off*8) = o.u;
  } else {
    *(uint4*)(dst + off*8) = ((const uint4*)src)[off];
  }
}

// ---------------------------------------------------------------------------
// Merged QKV projection, 64m x 128n tiles, 4 waves/block, triple-buffered
// global_load_lds, counted vmcnt + raw s_barrier (round-12 best, 221.1us) +
// T2 bank swizzle (conflicts=0) + fused RoPE-K / V-transpose epilogues.
// Grid 24 x 32 = 768 blocks (3/CU).  [T1 XCD swizzle reverted: round-14
// showed it inverts the small/large operand working sets (FETCH 40->53MB).]
// ---------------------------------------------------------------------------
__global__ __launch_bounds__(256, 4)
void gemm_qkv(const u16* __restrict__ A,
              const u16* __restrict__ wq, const u16* __restrict__ wk,
              const u16* __restrict__ wv,
              u16* __restrict__ Qb, u16* __restrict__ Kb, u16* __restrict__ Vtg,
              const u16* __restrict__ cosb, const u16* __restrict__ sinb)
{
  __shared__ __align__(16) u16 As[3][64][32];    // 12 KB
  __shared__ __align__(16) u16 Bs[3][128][32];   // 24 KB
  const int tid  = threadIdx.x;
  const int wave = tid >> 6;
  const int lane = tid & 63;
  const int quad = lane >> 4;
  const int l16  = lane & 15;
  const int m0 = blockIdx.y * 64;
  const int n0 = blockIdx.x * 128;
  const int wm = (wave & 1) * 32;
  const int wn = (wave >> 1) * 64;
  const int K = DMODEL;
  const int lr = lane >> 2;                      // 0..15 row within chunk
  const int lcs = (((lane & 3) ^ ((lr >> 1) & 3)) * 8);  // swizzled src col
  const int rc  = (quad ^ ((l16 >> 1) & 3)) * 8;         // swizzled read col

  const u16* Bb; int mode, nc0;      // 0=Q, 1=K(rope), 2=V(transpose)
  if (n0 < 2048)      { Bb = wq + (size_t)n0 * K;          mode = 0; nc0 = n0; }
  else if (n0 < 2560) { Bb = wk + (size_t)(n0 - 2048) * K; mode = 1; nc0 = n0 - 2048; }
  else                { Bb = wv + (size_t)(n0 - 2560) * K; mode = 2; nc0 = n0 - 2560; }

  f32x4 acc[2][4];
  #pragma unroll
  for (int i = 0; i < 2; i++)
    #pragma unroll
    for (int j = 0; j < 4; j++)
      acc[i][j] = (f32x4){0.f, 0.f, 0.f, 0.f};

  // wave w stages: A chunk w (rows 16w..16w+15), B chunks w and w+4 (3 loads)
  #define STAGE_QKV(b, k0)                                                        \
    do {                                                                          \
      glds16(A + (size_t)(m0 + 16*wave + lr) * K + (k0) + lcs,                    \
             (char*)&As[b][0][0] + wave*1024);                                    \
      glds16(Bb + (size_t)(16*wave + lr) * K + (k0) + lcs,                        \
             (char*)&Bs[b][0][0] + wave*1024);                                    \
      glds16(Bb + (size_t)(64 + 16*wave + lr) * K + (k0) + lcs,                   \
             (char*)&Bs[b][0][0] + (4+wave)*1024);                                \
    } while (0)

  const int NT = K / 32;             // 64
  STAGE_QKV(0, 0);
  STAGE_QKV(1, 32);
  STAGE_QKV(2, 64);
  int cur = 0;
  for (int t = 0; t < NT; ++t) {
    if      (t < NT - 2) wait_vm6();
    else if (t == NT - 2) wait_vm3();
    else                  wait_vm0();
    raw_barrier();                   // all waves' tile-t data visible
    mem_pin();
    bf16x8 af[2], bfr[4];
    #pragma unroll
    for (int i = 0; i < 2; i++) af[i]  = *(const bf16x8*)&As[cur][wm + i*16 + l16][rc];
    #pragma unroll
    for (int j = 0; j < 4; j++) bfr[j] = *(const bf16x8*)&Bs[cur][wn + j*16 + l16][rc];
    #pragma unroll
    for (int i = 0; i < 2; i++)
      #pragma unroll
      for (int j = 0; j < 4; j++)
        acc[i][j] = __builtin_amdgcn_mfma_f32_16x16x32_bf16(af[i], bfr[j], acc[i][j], 0, 0, 0);
    raw_barrier();                   // all waves' reads of buf[cur] done
    mem_pin();
    if (t + 3 < NT) STAGE_QKV(cur, (t + 3) * 32);
    cur = (cur == 2) ? 0 : cur + 1;
  }
  #undef STAGE_QKV

  if (mode == 0) {                   // ---- Q: plain bf16 store ----
    #pragma unroll
    for (int i = 0; i < 2; i++) {
      const int rb = m0 + wm + i*16 + quad*4;
      #pragma unroll
      for (int j = 0; j < 4; j++) {
        const int col = nc0 + wn + j*16 + l16;
        #pragma unroll
        for (int r = 0; r < 4; r++)
          Qb[(size_t)(rb + r) * QN + col] = f2bf(acc[i][j][r]);
      }
    }
  } else if (mode == 1) {            // ---- K: fused RoPE (f32, pre-round) ----
    const int hc = nc0 + wn;         // head col base (multiple of 64)
    #pragma unroll
    for (int i = 0; i < 2; i++) {
      const int rb = m0 + wm + i*16 + quad*4;
      #pragma unroll
      for (int j = 0; j < 2; j++) {
        const int d = j*16 + l16;    // 0..31; partner at d+32 is acc[i][j+2]
        #pragma unroll
        for (int r = 0; r < 4; r++) {
          const int s = rb + r;
          const float c  = bf2f(cosb[s*64 + d]);
          const float sn = bf2f(sinb[s*64 + d]);
          const float x1 = acc[i][j][r], x2 = acc[i][j+2][r];
          Kb[(size_t)s * KVNN + hc + d]      = f2bf(x1*c - x2*sn);
          Kb[(size_t)s * KVNN + hc + d + 32] = f2bf(x2*c + x1*sn);
        }
      }
    }
  } else {                           // ---- V: fused transpose into Vtg ----
    const int hkv = (nc0 + wn) >> 6;
    #pragma unroll
    for (int i = 0; i < 2; i++) {
      const int sbase = m0 + wm + i*16 + quad*4;
      #pragma unroll
      for (int j = 0; j < 4; j++) {
        const int d = j*16 + l16;
        union { u16 h[4]; uint2 v; } ok;
        #pragma unroll
        for (int r = 0; r < 4; r++) ok.h[r] = f2bf(acc[i][j][r]);
        *(uint2*)(Vtg + (size_t)(hkv*64 + d) * SEQ + sbase) = ok.v;
      }
    }
  }
}

// ---------------------------------------------------------------------------
// O-projection GEMM, triple-buffered counted-vmcnt + raw s_barrier + T2
// swizzle. Grid 16 x 32 = 512 blocks.
// ---------------------------------------------------------------------------
__global__ __launch_bounds__(256, 4)
void gemm_nt(const u16* __restrict__ A, const u16* __restrict__ B,
             void* __restrict__ C, int M, int N, int K,
             const uint32_t* outprobe)
{
  __shared__ __align__(16) u16 As[3][64][32];
  __shared__ __align__(16) u16 Bs[3][128][32];
  const int tid  = threadIdx.x;
  const int wave = tid >> 6;
  const int lane = tid & 63;
  const int quad = lane >> 4;
  const int l16  = lane & 15;
  const int m0 = blockIdx.y * 64;
  const int n0 = blockIdx.x * 128;
  const int wm = (wave & 1) * 32;
  const int wn = (wave >> 1) * 64;
  const int lr = lane >> 2;
  const int lcs = (((lane & 3) ^ ((lr >> 1) & 3)) * 8);
  const int rc  = (quad ^ ((l16 >> 1) & 3)) * 8;

  f32x4 acc[2][4];
  #pragma unroll
  for (int i = 0; i < 2; i++)
    #pragma unroll
    for (int j = 0; j < 4; j++)
      acc[i][j] = (f32x4){0.f, 0.f, 0.f, 0.f};

  #define STAGE_NT(b, k0)                                                         \
    do {                                                                          \
      glds16(A + (size_t)(m0 + 16*wave + lr) * K + (k0) + lcs,                    \
             (char*)&As[b][0][0] + wave*1024);                                    \
      glds16(B + (size_t)(n0 + 16*wave + lr) * K + (k0) + lcs,                    \
             (char*)&Bs[b][0][0] + wave*1024);                                    \
      glds16(B + (size_t)(n0 + 64 + 16*wave + lr) * K + (k0) + lcs,               \
             (char*)&Bs[b][0][0] + (4+wave)*1024);                                \
    } while (0)

  const int NT = K / 32;
  STAGE_NT(0, 0);
  STAGE_NT(1, 32);
  STAGE_NT(2, 64);
  int cur = 0;
  for (int t = 0; t < NT; ++t) {
    if      (t < NT - 2) wait_vm6();
    else if (t == NT - 2) wait_vm3();
    else                  wait_vm0();
    raw_barrier();
    mem_pin();
    bf16x8 af[2], bfr[4];
    #pragma unroll
    for (int i = 0; i < 2; i++) af[i]  = *(const bf16x8*)&As[cur][wm + i*16 + l16][rc];
    #pragma unroll
    for (int j = 0; j < 4; j++) bfr[j] = *(const bf16x8*)&Bs[cur][wn + j*16 + l16][rc];
    #pragma unroll
    for (int i = 0; i < 2; i++)
      #pragma unroll
      for (int j = 0; j < 4; j++)
        acc[i][j] = __builtin_amdgcn_mfma_f32_16x16x32_bf16(af[i], bfr[j], acc[i][j], 0, 0, 0);
    raw_barrier();
    mem_pin();
    if (t + 3 < NT) STAGE_NT(cur, (t + 3) * 32);
    cur = (cur == 2) ? 0 : cur + 1;
  }
  #undef STAGE_NT

  const bool f32out = (outprobe != nullptr) && probe_is_f32(outprobe);
  #pragma unroll
  for (int i = 0; i < 2; i++) {
    const int rb = m0 + wm + i*16 + quad*4;
    #pragma unroll
    for (int j = 0; j < 4; j++) {
      const int col = n0 + wn + j*16 + l16;
      if (f32out) {
        float* Cf = (float*)C;
        #pragma unroll
        for (int r = 0; r < 4; r++)
          Cf[(size_t)(rb + r) * N + col] = acc[i][j][r];
      } else {
        u16* Ch = (u16*)C;
        #pragma unroll
        for (int r = 0; r < 4; r++)
          Ch[(size_t)(rb + r) * N + col] = f2bf(acc[i][j][r]);
      }
    }
  }
}

// ---------------------------------------------------------------------------
// Causal GQA flash attention v9 (round-8/10/11/12 proven, unchanged):
// operand-swapped MFMAs, lane-local softmax, exp2 domain, packed stores.
// ---------------------------------------------------------------------------
#define LOG2E 1.4426950408889634f

__global__ __launch_bounds__(256, 4)
void attn_kernel(const u16* __restrict__ Qb,   // [SEQ][2048] pre-rope
                 const u16* __restrict__ Kb,   // [SEQ][512]  RoPE'd
                 const u16* __restrict__ Vtg,  // [8][64][SEQ]
                 u16* __restrict__ Ob,         // [SEQ][2048]
                 const u16* __restrict__ cosb, const u16* __restrict__ sinb)
{
  __shared__ __align__(16) u16 Ks[64][72];     // [key][d]
  __shared__ __align__(16) u16 Vt[64][72];     // [d][key]
  __shared__ __align__(16) u16 Ps[4][16][72];  // per-wave P round-trip [query][key]

  const int tid  = threadIdx.x;
  const int wave = tid >> 6;
  const int lane = tid & 63;
  const int quad = lane >> 4;
  const int l16  = lane & 15;
  const int h    = blockIdx.x;                 // 0..31
  const int qt   = 31 - blockIdx.y;            // heavy 64-row tiles first
  const int hkv  = h >> 2;
  const int qrow0 = qt * 64 + wave * 16;
  const int ktmax = qt + 1;
  const int myq  = qrow0 + l16;                // this lane's query row

  // ---- one-time Q load + fused RoPE + 1/8 scale (A/B-layout frags) ----
  bf16x8 qf[2];
  {
    const int qrow = qrow0 + l16;
    const u16* qp = Qb + (size_t)qrow * QN + h*64 + quad*8;
    union { bf16x8 v; u16 h8[8]; } lo, hi, cv, sv, olo, ohi;
    lo.v = *(const bf16x8*)qp;
    hi.v = *(const bf16x8*)(qp + 32);
    cv.v = *(const bf16x8*)(cosb + qrow*64 + quad*8);   // cos[d+32]==cos[d]
    sv.v = *(const bf16x8*)(sinb + qrow*64 + quad*8);
    #pragma unroll
    for (int j = 0; j < 8; j++) {
      const float x1 = bf2f(lo.h8[j]), x2 = bf2f(hi.h8[j]);
      const float c = bf2f(cv.h8[j]), sn = bf2f(sv.h8[j]);
      olo.h8[j] = f2bf((x1*c - x2*sn) * 0.125f);
      ohi.h8[j] = f2bf((x2*c + x1*sn) * 0.125f);
    }
    qf[0] = olo.v;
    qf[1] = ohi.v;
  }

  // oacc[nt][r]: d = nt*16 + quad*4 + r, query = l16 (lane-local!)
  f32x4 oacc[4];
  #pragma unroll
  for (int nt = 0; nt < 4; nt++) oacc[nt] = (f32x4){0.f, 0.f, 0.f, 0.f};
  float m_run = -1e30f, l_run = 0.f;           // per-lane (query = myq)

  const int sr = tid >> 3;          // 0..31
  const int sc = (tid & 7) * 8;     // 0..56

  // ---- register prefetch of tile 0 ----
  uint4 k0, k1, v0, v1;
  {
    k0 = *(const uint4*)(Kb + (size_t)(sr)      * KVNN + hkv*64 + sc);
    k1 = *(const uint4*)(Kb + (size_t)(sr + 32) * KVNN + hkv*64 + sc);
    v0 = *(const uint4*)(Vtg + (size_t)(hkv*64 + sr)      * SEQ + sc);
    v1 = *(const uint4*)(Vtg + (size_t)(hkv*64 + sr + 32) * SEQ + sc);
  }

  for (int kt = 0; kt < ktmax; kt++) {
    const int kb = kt * 64;
    const bool diag = (kt == qt);

    __syncthreads();                 // all waves done reading LDS (prev iter)
    *(uint4*)&Ks[sr][sc]      = k0;
    *(uint4*)&Ks[sr + 32][sc] = k1;
    *(uint4*)&Vt[sr][sc]      = v0;  // Vt row = d, col = key (pre-transposed)
    *(uint4*)&Vt[sr + 32][sc] = v1;
    __syncthreads();

    // ---- issue next tile's staging loads (latency hides behind compute) ----
    if (kt + 1 < ktmax) {
      const int kn = kb + 64;
      k0 = *(const uint4*)(Kb + (size_t)(kn + sr)      * KVNN + hkv*64 + sc);
      k1 = *(const uint4*)(Kb + (size_t)(kn + sr + 32) * KVNN + hkv*64 + sc);
      v0 = *(const uint4*)(Vtg + (size_t)(hkv*64 + sr)      * SEQ + kn + sc);
      v1 = *(const uint4*)(Vtg + (size_t)(hkv*64 + sr + 32) * SEQ + kn + sc);
    }

    // ---- S = K @ Q^T (swapped): sacc[nt][r] = S[key=kb+nt*16+quad*4+r][myq]
    f32x4 sacc[4];
    #pragma unroll
    for (int nt = 0; nt < 4; nt++) sacc[nt] = (f32x4){0.f, 0.f, 0.f, 0.f};
    #pragma unroll
    for (int ks = 0; ks < 2; ks++)
      #pragma unroll
      for (int nt = 0; nt < 4; nt++)
        if (!diag || nt <= wave) {
          bf16x8 kf = *(const bf16x8*)&Ks[nt*16 + l16][ks*32 + quad*8];
          sacc[nt] = __builtin_amdgcn_mfma_f32_16x16x32_bf16(kf, qf[ks], sacc[nt], 0, 0, 0);
        }
    // ---- to log2 domain ----
    #pragma unroll
    for (int nt = 0; nt < 4; nt++)
      #pragma unroll
      for (int r = 0; r < 4; r++)
        sacc[nt][r] *= LOG2E;
    // ---- causal mask (diagonal tile only): key > query ----
    if (diag) {
      #pragma unroll
      for (int nt = 0; nt < 4; nt++)
        #pragma unroll
        for (int r = 0; r < 4; r++)
          if (kb + nt*16 + quad*4 + r > myq)
            sacc[nt][r] = -1e30f;
    }
    // ---- online softmax: in-lane over 16 + 2 shfl across quads ----
    float mx = sacc[0][0];
    #pragma unroll
    for (int nt = 0; nt < 4; nt++)
      #pragma unroll
      for (int r = 0; r < 4; r++)
        if (nt | r) mx = fmaxf(mx, sacc[nt][r]);
    mx = fmaxf(mx, __shfl_xor(mx, 16));
    mx = fmaxf(mx, __shfl_xor(mx, 32));
    const float mnew = fmaxf(m_run, mx);
    const float alpha = fexp2(m_run - mnew);
    m_run = mnew;
    float rs = 0.f;
    #pragma unroll
    for (int nt = 0; nt < 4; nt++)
      #pragma unroll
      for (int r = 0; r < 4; r++) {
        const float p = fexp2(sacc[nt][r] - mnew);
        sacc[nt][r] = p;
        rs += p;
      }
    rs += __shfl_xor(rs, 16);
    rs += __shfl_xor(rs, 32);
    l_run = l_run * alpha + rs;
    // ---- write P packed (4 keys per b64): Ps[wave][query][key] ----
    #pragma unroll
    for (int nt = 0; nt < 4; nt++) {
      union { u16 h[4]; uint2 v; } pk;
      #pragma unroll
      for (int r = 0; r < 4; r++) pk.h[r] = f2bf(sacc[nt][r]);
      *(uint2*)&Ps[wave][l16][nt*16 + quad*4] = pk.v;
    }
    // ---- rescale O (alpha is lane-local) ----
    #pragma unroll
    for (int nt = 0; nt < 4; nt++)
      #pragma unroll
      for (int r = 0; r < 4; r++)
        oacc[nt][r] *= alpha;
    // keep Ps vector loads below the stores (wave-private, in-order)
    asm volatile("" ::: "memory");
    // ---- O += V @ P^T (swapped): out rows = d, cols = query ----
    #pragma unroll
    for (int ks = 0; ks < 2; ks++) {
      if (diag && wave < 2 && ks == 1) continue;  // keys 32..63 fully masked
      bf16x8 pf = *(const bf16x8*)&Ps[wave][l16][ks*32 + quad*8];
      #pragma unroll
      for (int nt = 0; nt < 4; nt++) {
        bf16x8 vf = *(const bf16x8*)&Vt[nt*16 + l16][ks*32 + quad*8];
        oacc[nt] = __builtin_amdgcn_mfma_f32_16x16x32_bf16(vf, pf, oacc[nt], 0, 0, 0);
      }
    }
  }

  // ---- epilogue (lane-local inv; packed 8B stores) ----
  {
    const float inv = 1.0f / l_run;
    #pragma unroll
    for (int nt = 0; nt < 4; nt++) {
      union { u16 h[4]; uint2 v; } ok;
      #pragma unroll
      for (int r = 0; r < 4; r++) ok.h[r] = f2bf(oacc[nt][r] * inv);
      *(uint2*)(Ob + (size_t)myq * QN + h*64 + nt*16 + quad*4) = ok.v;
    }
  }
}

// ---------------------------------------------------------------------------
extern "C" void kernel_launch(void* const* d_in, const int* in_sizes, int n_in,
                              void* d_out, int out_size, void* d_ws, size_t ws_size,
                              hipStream_t stream) {
  const void* X    = d_in[0];
  const void* cosr = d_in[1];
  const void* sinr = d_in[2];
  const void* wq   = d_in[3];
  const void* wk   = d_in[4];
  const void* wv   = d_in[5];
  const void* wo   = d_in[6];

  char* ws = (char*)d_ws;
  const size_t MB = 1024u * 1024u;
  u16* Xc   = (u16*)(ws);                      // 8 MB
  u16* wqc  = (u16*)(ws + 8*MB);               // 8 MB (Ab aliases after QKV gemm)
  u16* wkc  = (u16*)(ws + 16*MB);              // 2 MB
  u16* wvc  = (u16*)(ws + 18*MB);              // 2 MB
  u16* woc  = (u16*)(ws + 20*MB);              // 8 MB
  u16* cosc = (u16*)(ws + 28*MB);              // 256 KB
  u16* sinc = (u16*)(ws + 28*MB + 256*1024);   // 256 KB
  u16* Qb   = (u16*)(ws + 28*MB + 512*1024);   // 8 MB
  u16* Kb   = (u16*)(ws + 36*MB + 512*1024);   // 2 MB
  u16* Vtg  = (u16*)(ws + 40*MB + 512*1024);   // 2 MB (written by gemm_qkv)
  u16* Ab   = wqc;   // wqc dead after gemm_qkv

  dim3 b256(256);
  conv_all<<<dim3(7296), b256, 0, stream>>>(X, cosr, sinr, wq, wk, wv, wo,
                                            Xc, cosc, sinc, wqc, wkc, wvc, woc);
  gemm_qkv<<<dim3(24, 32), b256, 0, stream>>>(Xc, wqc, wkc, wvc, Qb, Kb, Vtg,
                                              cosc, sinc);
  attn_kernel<<<dim3(NQH, SEQ/64), b256, 0, stream>>>(Qb, Kb, Vtg, Ab, cosc, sinc);
  gemm_nt<<<dim3(16, 32), b256, 0, stream>>>(Ab, woc, d_out, SEQ, DMODEL, DMODEL,
                                             (const uint32_t*)cosr);
}